// Round 1
// baseline (63.953 us; speedup 1.0000x reference)
//
#include <hip/hip_runtime.h>

#define TPB 256
#define PRED_CH 30
#define GT_CH 25

// IEEE-exact helpers: prevent fma contraction so the IoU chain matches numpy
// float32 bit-for-bit (argmax flips would cost absmax=1.0 on obj_ij).
__device__ __forceinline__ float mul_rn(float a, float b) { return __fmul_rn(a, b); }
__device__ __forceinline__ float add_rn(float a, float b) { return __fadd_rn(a, b); }
__device__ __forceinline__ float sub_rn(float a, float b) { return __fsub_rn(a, b); }

// (x,y,w,h) normalized -> xyxy pixels; zero box if all inputs zero.
// Matches reference order: cx = 64*(x+gi); W = w*448; xyxy = cx -/+ W/2.
__device__ __forceinline__ void to_xyxy(float x, float y, float w, float h,
                                        float gi, float gj, float o[4]) {
    float cx = mul_rn(64.0f, add_rn(x, gi));
    float cy = mul_rn(64.0f, add_rn(y, gj));
    float W  = mul_rn(w, 448.0f);
    float H  = mul_rn(h, 448.0f);
    float Wh = mul_rn(W, 0.5f);   // exact halving, same as W/2
    float Hh = mul_rn(H, 0.5f);
    o[0] = sub_rn(cx, Wh);
    o[1] = sub_rn(cy, Hh);
    o[2] = add_rn(cx, Wh);
    o[3] = add_rn(cy, Hh);
    if (x == 0.0f && y == 0.0f && w == 0.0f && h == 0.0f) {
        o[0] = o[1] = o[2] = o[3] = 0.0f;
    }
}

__device__ __forceinline__ float iou_box(const float* pb /* conf,x,y,w,h */,
                                         const float gb[4], float areag,
                                         float gi, float gj) {
    float p[4];
    to_xyxy(pb[1], pb[2], pb[3], pb[4], gi, gj, p);
    float lx = fmaxf(gb[0], p[0]);
    float ly = fmaxf(gb[1], p[1]);
    float rx = fminf(gb[2], p[2]);
    float ry = fminf(gb[3], p[3]);
    float iw = fmaxf(sub_rn(rx, lx), 0.0f);
    float ih = fmaxf(sub_rn(ry, ly), 0.0f);
    float inter = mul_rn(iw, ih);
    float areap = mul_rn(sub_rn(p[2], p[0]), sub_rn(p[3], p[1]));
    // reference: inter / (area_g + area_p - inter), left-to-right
    float denom = sub_rn(add_rn(areag, areap), inter);
    return __fdiv_rn(inter, denom);
}

__global__ __launch_bounds__(TPB) void yolo_main(const float* __restrict__ pred,
                                                 const float* __restrict__ gt,
                                                 float* __restrict__ out,
                                                 int ncells, float inv_b) {
    __shared__ float sp[TPB * PRED_CH];   // 30720 B
    __shared__ float sg[TPB * GT_CH];     // 25600 B
    __shared__ float wsum[TPB / 64];

    const int tid    = threadIdx.x;
    const int block0 = blockIdx.x * TPB;

    // ---- stage pred tile: 1920 float4 per full block, coalesced ----
    {
        const float4* p4 = reinterpret_cast<const float4*>(pred) + (size_t)blockIdx.x * (TPB * PRED_CH / 4);
        float4* s4 = reinterpret_cast<float4*>(sp);
        const size_t n4_total = (size_t)ncells * PRED_CH / 4;
        const size_t base4 = (size_t)blockIdx.x * (TPB * PRED_CH / 4);
#pragma unroll
        for (int k = 0; k < (TPB * PRED_CH / 4 + TPB - 1) / TPB; ++k) {
            int idx = tid + k * TPB;
            if (idx < TPB * PRED_CH / 4 && base4 + idx < n4_total) s4[idx] = p4[idx];
        }
    }
    // ---- stage gt tile: 1600 float4 per full block ----
    {
        const float4* g4 = reinterpret_cast<const float4*>(gt) + (size_t)blockIdx.x * (TPB * GT_CH / 4);
        float4* s4 = reinterpret_cast<float4*>(sg);
        const size_t n4_total = (size_t)ncells * GT_CH / 4;
        const size_t base4 = (size_t)blockIdx.x * (TPB * GT_CH / 4);
#pragma unroll
        for (int k = 0; k < (TPB * GT_CH / 4 + TPB - 1) / TPB; ++k) {
            int idx = tid + k * TPB;
            if (idx < TPB * GT_CH / 4 && base4 + idx < n4_total) s4[idx] = g4[idx];
        }
    }
    __syncthreads();

    const int cell = block0 + tid;
    float lsum = 0.0f;
    if (cell < ncells) {
        const float* P = &sp[tid * PRED_CH];  // LDS stride 30: 2-way bank alias (free)
        const float* G = &sg[tid * GT_CH];    // stride 25: conflict-free

        const float gm = (G[20] == 1.0f) ? 1.0f : 0.0f;

        // class loss: sum_{c<20} (p-g)^2 * mask   (loose threshold, fma ok)
        float cl = 0.0f;
#pragma unroll
        for (int c = 0; c < 20; ++c) {
            float d = P[c] - G[c];
            cl = fmaf(d, d, cl);
        }
        lsum = cl * gm;

        // grid indices: cell = (b*7 + i)*7 + j ; cx uses i (axis1), cy uses j (axis2)
        const int rem = cell % 49;
        const int ii  = rem / 7;
        const float gi = (float)ii;
        const float gj = (float)(rem - ii * 7);

        float gb[4];
        to_xyxy(G[21], G[22], G[23], G[24], gi, gj, gb);
        const float areag = mul_rn(sub_rn(gb[2], gb[0]), sub_rn(gb[3], gb[1]));

        const float iou0 = iou_box(P + 20, gb, areag, gi, gj);
        const float iou1 = iou_box(P + 25, gb, areag, gi, gj);

        // numpy argmax: first max wins on ties
        const int sel = (iou1 > iou0) ? 1 : 0;

        out[1 + 2 * (size_t)cell]     = (sel == 0) ? gm : 0.0f;
        out[1 + 2 * (size_t)cell + 1] = (sel == 1) ? gm : 0.0f;
    }

    // ---- block reduce class loss, one atomic per block ----
#pragma unroll
    for (int off = 32; off > 0; off >>= 1) lsum += __shfl_down(lsum, off);
    const int wid = tid >> 6, lane = tid & 63;
    if (lane == 0) wsum[wid] = lsum;
    __syncthreads();
    if (tid == 0) {
        float s = wsum[0] + wsum[1] + wsum[2] + wsum[3];
        atomicAdd(out, s * inv_b);
    }
}

extern "C" void kernel_launch(void* const* d_in, const int* in_sizes, int n_in,
                              void* d_out, int out_size, void* d_ws, size_t ws_size,
                              hipStream_t stream) {
    const float* pred = (const float*)d_in[0];
    const float* gt   = (const float*)d_in[1];
    float* out = (float*)d_out;

    const int ncells = in_sizes[0] / PRED_CH;      // B*7*7
    const int batch  = ncells / 49;
    const int blocks = (ncells + TPB - 1) / TPB;

    // zero the scalar-loss slot (graph-capture safe: async on stream)
    hipMemsetAsync(d_out, 0, sizeof(float), stream);
    yolo_main<<<blocks, TPB, 0, stream>>>(pred, gt, out, ncells, 1.0f / (float)batch);
}